// Round 8
// baseline (83.601 us; speedup 1.0000x reference)
//
#include <hip/hip_runtime.h>

#define DM 2048
#define NG 64
#define TPB 32          // tokens per block
#define WKK 256         // k per window (1 KB per token row per visit)
#define NWIN 8
#define EPSV 1e-8f

typedef __attribute__((ext_vector_type(4))) float f32x4;
typedef __attribute__((ext_vector_type(4))) int i32x4;
typedef __attribute__((ext_vector_type(4))) unsigned int u32x4;
typedef __attribute__((ext_vector_type(8))) short bf16x8;

__device__ __forceinline__ void stage16(const float* gsrc, float* ldst) {
  __builtin_amdgcn_global_load_lds(
      (const __attribute__((address_space(1))) unsigned int*)gsrc,
      (__attribute__((address_space(3))) unsigned int*)ldst, 16, 0, 0);
}

// split 8 fp32 into hi (truncate) / lo (rne residual) bf16.
__device__ __forceinline__ void split8(f32x4 x0, f32x4 x1, bf16x8& ah, bf16x8& al) {
  u32x4 u0 = __builtin_bit_cast(u32x4, x0);
  u32x4 u1 = __builtin_bit_cast(u32x4, x1);
  i32x4 hi;
  hi.x = (int)((u0.x >> 16) | (u0.y & 0xffff0000u));
  hi.y = (int)((u0.z >> 16) | (u0.w & 0xffff0000u));
  hi.z = (int)((u1.x >> 16) | (u1.y & 0xffff0000u));
  hi.w = (int)((u1.z >> 16) | (u1.w & 0xffff0000u));
  u32x4 m0 = u0 & 0xffff0000u;
  u32x4 m1 = u1 & 0xffff0000u;
  f32x4 r0 = x0 - __builtin_bit_cast(f32x4, m0);
  f32x4 r1 = x1 - __builtin_bit_cast(f32x4, m1);
  int lo0, lo1, lo2, lo3;
  asm("v_cvt_pk_bf16_f32 %0, %1, %2" : "=v"(lo0) : "v"(r0.x), "v"(r0.y));
  asm("v_cvt_pk_bf16_f32 %0, %1, %2" : "=v"(lo1) : "v"(r0.z), "v"(r0.w));
  asm("v_cvt_pk_bf16_f32 %0, %1, %2" : "=v"(lo2) : "v"(r1.x), "v"(r1.y));
  asm("v_cvt_pk_bf16_f32 %0, %1, %2" : "=v"(lo3) : "v"(r1.z), "v"(r1.w));
  i32x4 lo; lo.x = lo0; lo.y = lo1; lo.z = lo2; lo.w = lo3;
  ah = __builtin_bit_cast(bf16x8, hi);
  al = __builtin_bit_cast(bf16x8, lo);
}

// ---------------- Kernel 0: W split (16x16x32 fragment table) ----------------
// Element (S,q,n,j): k = S*32 + q*8 + j, stored at ((S*4+q)*64+n)*8 + j.
__global__ __launch_bounds__(256) void moe_prep(
    const float* __restrict__ W, unsigned short* __restrict__ whp,
    unsigned short* __restrict__ wlp, int* __restrict__ counter)
{
  int tg = blockIdx.x * 256 + threadIdx.x;   // 64*4*64 = 16384 fragments
  if (tg == 0) *counter = 0;
  int S = tg >> 8, q = (tg >> 6) & 3, n = tg & 63;
  const float* src = &W[(size_t)n * DM + S * 32 + q * 8];
  f32x4 w0 = *(const f32x4*)&src[0];
  f32x4 w1 = *(const f32x4*)&src[4];
  bf16x8 ah, al;
  split8(w0, w1, ah, al);
  *(bf16x8*)&whp[(size_t)tg * 8] = ah;
  *(bf16x8*)&wlp[(size_t)tg * 8] = al;
}

// ---------------- Kernel 1: fully fused GEMM + reduce + softmax/top-8 ----------------
// Block = 32 tokens x 64 groups x full K. 4 waves; wave w owns k-sub [64w,64w+64)
// of each 256-k window. In-block cross-wave k-reduce, fused epilogue, flag.
__global__ __launch_bounds__(256, 2) void moe_fused(
    const float* __restrict__ x, const unsigned short* __restrict__ whp,
    const unsigned short* __restrict__ wlp, float* __restrict__ out,
    int* __restrict__ counter, int* __restrict__ flaglist, int mtok)
{
  __shared__ float xs[2][TPB * WKK];   // 64 KB total

  const int tid  = threadIdx.x;
  const int lane = tid & 63;
  const int wv   = tid >> 6;          // 0..3
  const int q4   = lane >> 4;         // k-chunk (A and B share this)
  const int l15  = lane & 15;
  const int tok0 = blockIdx.x * TPB;

  // stage one 32x256 window; each 64-thread wave covers one row's 1 KB
  // contiguously (XOR-permuted quads); LDS dest linear.
  auto stage_window = [&](int win, int slot) {
    const float* xb = x + (size_t)tok0 * DM + win * WKK;
    float* ld = &xs[slot][0];
#pragma unroll
    for (int i = 0; i < 8; ++i) {
      int idx = i * 256 + tid;
      int r = idx >> 6, dq = idx & 63;
      int sq = dq ^ (r & 15);
      stage16(xb + (size_t)r * DM + (sq << 2), ld + (idx << 2));
    }
  };

  f32x4 acc[2][4] = {};
  bf16x8 Bh[2][4], Bl[2][4];

#define LOADB(WIN) do {                                                      \
    _Pragma("unroll")                                                        \
    for (int ss = 0; ss < 2; ++ss) {                                         \
      int S_ = (WIN) * 8 + wv * 2 + ss;                                      \
      _Pragma("unroll")                                                      \
      for (int nt = 0; nt < 4; ++nt) {                                       \
        size_t bi_ = (((size_t)S_ * 4 + q4) * 64 + nt * 16 + l15) * 8;       \
        Bh[ss][nt] = *(const bf16x8*)&whp[bi_];                              \
        Bl[ss][nt] = *(const bf16x8*)&wlp[bi_];                              \
      }                                                                      \
    }                                                                        \
  } while (0)

#define COMPUTE(WIN) do {                                                    \
    const float* xb_ = &xs[(WIN) & 1][0];                                    \
    _Pragma("unroll")                                                        \
    for (int ss = 0; ss < 2; ++ss) {                                         \
      _Pragma("unroll")                                                      \
      for (int mt = 0; mt < 2; ++mt) {                                       \
        int row_ = mt * 16 + l15;                                            \
        int qa_ = 16 * wv + 8 * ss + 2 * q4;                                 \
        f32x4 x0 = *(const f32x4*)&xb_[row_ * WKK + ((qa_ ^ l15) << 2)];     \
        f32x4 x1 = *(const f32x4*)&xb_[row_ * WKK + (((qa_ + 1) ^ l15) << 2)]; \
        bf16x8 ah, al;                                                       \
        split8(x0, x1, ah, al);                                              \
        _Pragma("unroll")                                                    \
        for (int nt = 0; nt < 4; ++nt) {                                     \
          acc[mt][nt] = __builtin_amdgcn_mfma_f32_16x16x32_bf16(ah, Bh[ss][nt], acc[mt][nt], 0, 0, 0); \
          acc[mt][nt] = __builtin_amdgcn_mfma_f32_16x16x32_bf16(al, Bh[ss][nt], acc[mt][nt], 0, 0, 0); \
          acc[mt][nt] = __builtin_amdgcn_mfma_f32_16x16x32_bf16(ah, Bl[ss][nt], acc[mt][nt], 0, 0, 0); \
        }                                                                    \
      }                                                                      \
    }                                                                        \
  } while (0)

  stage_window(0, 0);
  __syncthreads();

#pragma unroll 1
  for (int win = 0; win < NWIN; ++win) {
    LOADB(win);                                 // 16 L2 loads first (oldest)
    __builtin_amdgcn_sched_barrier(0);          // stage issues after B loads
    if (win < NWIN - 1) stage_window(win + 1, (win + 1) & 1);
    COMPUTE(win);                               // B-wait = vmcnt(8), x streaming
    __syncthreads();
  }
#undef LOADB
#undef COMPUTE

  // ---- cross-wave k-reduce via LDS (alias xs[0]: 4 x 32 x 64 f32 = 32 KB) ----
  float* red = &xs[0][0];
#pragma unroll
  for (int mt = 0; mt < 2; ++mt)
#pragma unroll
    for (int nt = 0; nt < 4; ++nt)
#pragma unroll
      for (int rg = 0; rg < 4; ++rg) {
        int m = mt * 16 + q4 * 4 + rg;          // C/D: row=(lane>>4)*4+reg
        int n = nt * 16 + l15;                  // C/D: col=lane&15
        red[wv * 2048 + m * 64 + ((n + 4 * m) & 63)] = acc[mt][nt][rg];
      }
  __syncthreads();

  // ---- fused epilogue: 8 lanes per token (validated round-2/7 math) ----
  const int t  = tid >> 3;            // token 0..31
  const int li = tid & 7;
  float l[8];
#pragma unroll
  for (int j = 0; j < 8; ++j) {
    int c = ((li * 8 + j) + 4 * t) & 63;
    l[j] = red[t * 64 + c] + red[2048 + t * 64 + c]
         + red[4096 + t * 64 + c] + red[6144 + t * 64 + c];
  }

  float m = l[0];
#pragma unroll
  for (int j = 1; j < 8; ++j) m = fmaxf(m, l[j]);
#pragma unroll
  for (int msk = 1; msk < 8; msk <<= 1) m = fmaxf(m, __shfl_xor(m, msk));

  float e[8];
  float sum = 0.f;
#pragma unroll
  for (int j = 0; j < 8; ++j) { e[j] = __expf(l[j] - m); sum += e[j]; }
#pragma unroll
  for (int msk = 1; msk < 8; msk <<= 1) sum += __shfl_xor(sum, msk);

  unsigned taken = 0;
  float esel = 0.f, e8 = 0.f, e9 = 0.f;
#pragma unroll 1
  for (int p = 0; p < 9; ++p) {
    float bv = -1.f;
    int bi = 127;
#pragma unroll
    for (int j = 0; j < 8; ++j) {
      bool avail = !((taken >> j) & 1u);
      float vv = e[j];
      int g = (li << 3) + j;
      bool better = avail && (vv > bv || (vv == bv && g < bi));
      bv = better ? vv : bv;
      bi = better ? g : bi;
    }
#pragma unroll
    for (int msk = 1; msk < 8; msk <<= 1) {
      float ov = __shfl_xor(bv, msk);
      int oi = __shfl_xor(bi, msk);
      bool better = (ov > bv) || (ov == bv && oi < bi);
      bv = better ? ov : bv;
      bi = better ? oi : bi;
    }
    if (p < 8) {
      esel += bv;
      if ((bi >> 3) == li) taken |= 1u << (bi & 7);
      if (p == 7) e8 = bv;
    } else {
      e9 = bv;
    }
  }

  // flag near-ties for exact recompute: logit gap < ~1e-3
  if (li == 0 && e9 > e8 * 0.999f) {
    int ix = atomicAdd(counter, 1);
    flaglist[ix] = tok0 + t;
  }

  const float inv = 1.f / sum;
  const float rsc = 1.f / (esel + EPSV * sum);
  const size_t MN = (size_t)mtok * NG;
  const size_t base = (size_t)(tok0 + t) * NG + (li << 3);

  f32x4 r0, r1, m0, m1, s0, s1;
#pragma unroll
  for (int j = 0; j < 4; ++j) {
    float bitL = ((taken >> j) & 1u) ? 1.f : 0.f;
    float bitH = ((taken >> (j + 4)) & 1u) ? 1.f : 0.f;
    s0[j] = e[j] * inv;      s1[j] = e[j + 4] * inv;
    m0[j] = bitL;            m1[j] = bitH;
    r0[j] = bitL * e[j] * rsc;
    r1[j] = bitH * e[j + 4] * rsc;
  }
  *(f32x4*)&out[base]              = r0;
  *(f32x4*)&out[base + 4]          = r1;
  *(f32x4*)&out[MN + base]         = m0;
  *(f32x4*)&out[MN + base + 4]     = m1;
  *(f32x4*)&out[2 * MN + base]     = s0;
  *(f32x4*)&out[2 * MN + base + 4] = s1;
}

// ---------------- Kernel 2: exact fp32 fixup, block-per-token ----------------
__global__ __launch_bounds__(256) void moe_fixup(
    const float* __restrict__ x, const float* __restrict__ W,
    float* __restrict__ out, const int* __restrict__ counter,
    const int* __restrict__ flaglist, int mtok)
{
  const int cnt = counter[0];
  const int g = threadIdx.x & 63;
  const int q = threadIdx.x >> 6;
  const size_t MN = (size_t)mtok * NG;
  __shared__ float part[4][64];

  for (int i = blockIdx.x; i < cnt; i += 256) {
    const int tok = flaglist[i];
    const float* xr = &x[(size_t)tok * DM + q * 512];
    const float* wr = &W[(size_t)g * DM + q * 512];
    f32x4 a = {0.f, 0.f, 0.f, 0.f};
#pragma unroll 8
    for (int k = 0; k < 512; k += 4)
      a += *(const f32x4*)&xr[k] * *(const f32x4*)&wr[k];
    part[q][g] = a.x + a.y + a.z + a.w;
    __syncthreads();

    if (q == 0) {
      float l = part[0][g] + part[1][g] + part[2][g] + part[3][g];

      float m = l;
#pragma unroll
      for (int msk = 1; msk < 64; msk <<= 1) m = fmaxf(m, __shfl_xor(m, msk));
      float e = __expf(l - m);
      float sum = e;
#pragma unroll
      for (int msk = 1; msk < 64; msk <<= 1) sum += __shfl_xor(sum, msk);

      bool sel = false;
#pragma unroll 1
      for (int p = 0; p < 8; ++p) {
        float bv = sel ? -3.4e38f : l;
        int bi = sel ? 1000 : g;
#pragma unroll
        for (int msk = 1; msk < 64; msk <<= 1) {
          float ov = __shfl_xor(bv, msk);
          int oi = __shfl_xor(bi, msk);
          bool better = (ov > bv) || (ov == bv && oi < bi);
          bv = better ? ov : bv;
          bi = better ? oi : bi;
        }
        if (bi == g) sel = true;
      }
      float esel = sel ? e : 0.f;
#pragma unroll
      for (int msk = 1; msk < 64; msk <<= 1) esel += __shfl_xor(esel, msk);

      const float inv = 1.f / sum;
      const float rsc = 1.f / (esel + EPSV * sum);
      const float bit = sel ? 1.f : 0.f;
      const size_t base = (size_t)tok * NG + g;
      out[base] = bit * e * rsc;
      out[MN + base] = bit;
      out[2 * MN + base] = e * inv;
    }
    __syncthreads();
  }
}

extern "C" void kernel_launch(void* const* d_in, const int* in_sizes, int n_in,
                              void* d_out, int out_size, void* d_ws, size_t ws_size,
                              hipStream_t stream) {
  const float* x = (const float*)d_in[0];
  const float* W = (const float*)d_in[1];
  float* out = (float*)d_out;
  const int mtok = in_sizes[0] / DM;          // 16384

  char* ws = (char*)d_ws;
  int* counter = (int*)ws;                               // @0
  int* flaglist = (int*)(ws + 4096);                     // 64 KB
  unsigned short* whp = (unsigned short*)(ws + 69632);   // 256 KB
  unsigned short* wlp = (unsigned short*)(ws + 331776);  // 256 KB

  hipLaunchKernelGGL(moe_prep, dim3(64), dim3(256), 0, stream, W, whp, wlp, counter);
  hipLaunchKernelGGL(moe_fused, dim3(mtok / TPB), dim3(256), 0, stream,
                     x, whp, wlp, out, counter, flaglist, mtok);
  hipLaunchKernelGGL(moe_fixup, dim3(256), dim3(256), 0, stream,
                     x, W, out, counter, flaglist, mtok);
}

// Round 9
// 77.042 us; speedup vs baseline: 1.0851x; 1.0851x over previous
//
#include <hip/hip_runtime.h>

#define DM 2048
#define NG 64
#define EPSV 1e-8f

typedef __attribute__((ext_vector_type(4))) float f32x4;
typedef __attribute__((ext_vector_type(4))) int i32x4;
typedef __attribute__((ext_vector_type(4))) unsigned int u32x4;
typedef __attribute__((ext_vector_type(8))) short bf16x8;

// split 8 fp32 into hi (truncate) / lo (rne residual) bf16.
__device__ __forceinline__ void split8(f32x4 x0, f32x4 x1, bf16x8& ah, bf16x8& al) {
  u32x4 u0 = __builtin_bit_cast(u32x4, x0);
  u32x4 u1 = __builtin_bit_cast(u32x4, x1);
  i32x4 hi;
  hi.x = (int)((u0.x >> 16) | (u0.y & 0xffff0000u));
  hi.y = (int)((u0.z >> 16) | (u0.w & 0xffff0000u));
  hi.z = (int)((u1.x >> 16) | (u1.y & 0xffff0000u));
  hi.w = (int)((u1.z >> 16) | (u1.w & 0xffff0000u));
  u32x4 m0 = u0 & 0xffff0000u;
  u32x4 m1 = u1 & 0xffff0000u;
  f32x4 r0 = x0 - __builtin_bit_cast(f32x4, m0);
  f32x4 r1 = x1 - __builtin_bit_cast(f32x4, m1);
  int lo0, lo1, lo2, lo3;
  asm("v_cvt_pk_bf16_f32 %0, %1, %2" : "=v"(lo0) : "v"(r0.x), "v"(r0.y));
  asm("v_cvt_pk_bf16_f32 %0, %1, %2" : "=v"(lo1) : "v"(r0.z), "v"(r0.w));
  asm("v_cvt_pk_bf16_f32 %0, %1, %2" : "=v"(lo2) : "v"(r1.x), "v"(r1.y));
  asm("v_cvt_pk_bf16_f32 %0, %1, %2" : "=v"(lo3) : "v"(r1.z), "v"(r1.w));
  i32x4 lo; lo.x = lo0; lo.y = lo1; lo.z = lo2; lo.w = lo3;
  ah = __builtin_bit_cast(bf16x8, hi);
  al = __builtin_bit_cast(bf16x8, lo);
}

// ---------------- Kernel 0: W split (16x16x32 fragment table) ----------------
// Element (S,q,n,j): k = S*32 + q*8 + j, stored at ((S*4+q)*64+n)*8 + j.
__global__ __launch_bounds__(256) void moe_prep(
    const float* __restrict__ W, unsigned short* __restrict__ whp,
    unsigned short* __restrict__ wlp, int* __restrict__ counter)
{
  int tg = blockIdx.x * 256 + threadIdx.x;   // 64*4*64 = 16384 fragments
  if (tg == 0) *counter = 0;
  int S = tg >> 8, q = (tg >> 6) & 3, n = tg & 63;
  const float* src = &W[(size_t)n * DM + S * 32 + q * 8];
  f32x4 w0 = *(const f32x4*)&src[0];
  f32x4 w1 = *(const f32x4*)&src[4];
  bf16x8 ah, al;
  split8(w0, w1, ah, al);
  *(bf16x8*)&whp[(size_t)tg * 8] = ah;
  *(bf16x8*)&wlp[(size_t)tg * 8] = al;
}

// ---------------- Kernel 1: barrier-free register-streaming GEMM + epilogue ----------------
// Block = 16 tokens, 4 waves. Wave wv: 16 tok x 64 grp x k-slice [512wv, 512wv+512),
// A-frags loaded straight from global (32 B contiguous per lane), B-frags from the
// L2-resident split table. No LDS, no barriers in the main loop. One syncthreads,
// 4-slice LDS reduce, fused validated softmax/top-8/write + near-tie flag.
__global__ __launch_bounds__(256, 4) void moe_gemm(
    const float* __restrict__ x, const unsigned short* __restrict__ whp,
    const unsigned short* __restrict__ wlp, float* __restrict__ out,
    int* __restrict__ counter, int* __restrict__ flaglist, int mtok)
{
  __shared__ float red[4 * 16 * 64];   // 16 KB

  const int tid  = threadIdx.x;
  const int lane = tid & 63;
  const int wv   = tid >> 6;          // k-slice 0..3
  const int q4   = lane >> 4;         // k-chunk within 32k step
  const int l15  = lane & 15;         // token row / B column
  const int tok0 = blockIdx.x * 16;

  // A: row (tok0+l15), k base = wv*512 + q4*8; 16 steps via imm offsets (128 B stride)
  const float* pa = x + (size_t)(tok0 + l15) * DM + wv * 512 + q4 * 8;
  // B: fragment unit index ((S*4+q4)*64 + nt*16 + l15); S = 16*wv + s
  const bf16x8* pbh = (const bf16x8*)whp + ((size_t)(16 * wv) * 4 + q4) * 64 + l15;
  const bf16x8* pbl = (const bf16x8*)wlp + ((size_t)(16 * wv) * 4 + q4) * 64 + l15;

  f32x4 acc0 = {}, acc1 = {}, acc2 = {}, acc3 = {};

#pragma unroll 2
  for (int s = 0; s < 16; ++s) {
    f32x4 x0 = *(const f32x4*)(pa + s * 32);
    f32x4 x1 = *(const f32x4*)(pa + s * 32 + 4);
    bf16x8 bh0 = pbh[0], bh1 = pbh[16], bh2 = pbh[32], bh3 = pbh[48];
    bf16x8 bl0 = pbl[0], bl1 = pbl[16], bl2 = pbl[32], bl3 = pbl[48];
    pbh += 256; pbl += 256;
    bf16x8 ah, al;
    split8(x0, x1, ah, al);
    acc0 = __builtin_amdgcn_mfma_f32_16x16x32_bf16(ah, bh0, acc0, 0, 0, 0);
    acc0 = __builtin_amdgcn_mfma_f32_16x16x32_bf16(al, bh0, acc0, 0, 0, 0);
    acc0 = __builtin_amdgcn_mfma_f32_16x16x32_bf16(ah, bl0, acc0, 0, 0, 0);
    acc1 = __builtin_amdgcn_mfma_f32_16x16x32_bf16(ah, bh1, acc1, 0, 0, 0);
    acc1 = __builtin_amdgcn_mfma_f32_16x16x32_bf16(al, bh1, acc1, 0, 0, 0);
    acc1 = __builtin_amdgcn_mfma_f32_16x16x32_bf16(ah, bl1, acc1, 0, 0, 0);
    acc2 = __builtin_amdgcn_mfma_f32_16x16x32_bf16(ah, bh2, acc2, 0, 0, 0);
    acc2 = __builtin_amdgcn_mfma_f32_16x16x32_bf16(al, bh2, acc2, 0, 0, 0);
    acc2 = __builtin_amdgcn_mfma_f32_16x16x32_bf16(ah, bl2, acc2, 0, 0, 0);
    acc3 = __builtin_amdgcn_mfma_f32_16x16x32_bf16(ah, bh3, acc3, 0, 0, 0);
    acc3 = __builtin_amdgcn_mfma_f32_16x16x32_bf16(al, bh3, acc3, 0, 0, 0);
    acc3 = __builtin_amdgcn_mfma_f32_16x16x32_bf16(ah, bl3, acc3, 0, 0, 0);
  }

  // acc -> LDS slice wv (rotate-swizzled cols). C/D: col = l15 (+16nt), row m = q4*4+rg.
#pragma unroll
  for (int rg = 0; rg < 4; ++rg) {
    int m = q4 * 4 + rg;
    int rot = 4 * m;
    red[wv * 1024 + m * 64 + (((0 * 16 + l15) + rot) & 63)] = acc0[rg];
    red[wv * 1024 + m * 64 + (((1 * 16 + l15) + rot) & 63)] = acc1[rg];
    red[wv * 1024 + m * 64 + (((2 * 16 + l15) + rot) & 63)] = acc2[rg];
    red[wv * 1024 + m * 64 + (((3 * 16 + l15) + rot) & 63)] = acc3[rg];
  }
  __syncthreads();

  // ---- epilogue: 16 tokens x 8 lanes (threads 0..127), validated math ----
  if (tid < 128) {
    const int t  = tid >> 3;
    const int li = tid & 7;
    float l[8];
#pragma unroll
    for (int j = 0; j < 8; ++j) {
      int c = ((li * 8 + j) + 4 * t) & 63;
      l[j] = red[t * 64 + c] + red[1024 + t * 64 + c]
           + red[2048 + t * 64 + c] + red[3072 + t * 64 + c];
    }

    float m = l[0];
#pragma unroll
    for (int j = 1; j < 8; ++j) m = fmaxf(m, l[j]);
#pragma unroll
    for (int msk = 1; msk < 8; msk <<= 1) m = fmaxf(m, __shfl_xor(m, msk));

    float e[8];
    float sum = 0.f;
#pragma unroll
    for (int j = 0; j < 8; ++j) { e[j] = __expf(l[j] - m); sum += e[j]; }
#pragma unroll
    for (int msk = 1; msk < 8; msk <<= 1) sum += __shfl_xor(sum, msk);

    unsigned taken = 0;
    float esel = 0.f, e8 = 0.f, e9 = 0.f;
#pragma unroll 1
    for (int p = 0; p < 9; ++p) {
      float bv = -1.f;
      int bi = 127;
#pragma unroll
      for (int j = 0; j < 8; ++j) {
        bool avail = !((taken >> j) & 1u);
        float vv = e[j];
        int g = (li << 3) + j;
        bool better = avail && (vv > bv || (vv == bv && g < bi));
        bv = better ? vv : bv;
        bi = better ? g : bi;
      }
#pragma unroll
      for (int msk = 1; msk < 8; msk <<= 1) {
        float ov = __shfl_xor(bv, msk);
        int oi = __shfl_xor(bi, msk);
        bool better = (ov > bv) || (ov == bv && oi < bi);
        bv = better ? ov : bv;
        bi = better ? oi : bi;
      }
      if (p < 8) {
        esel += bv;
        if ((bi >> 3) == li) taken |= 1u << (bi & 7);
        if (p == 7) e8 = bv;
      } else {
        e9 = bv;
      }
    }

    if (li == 0 && e9 > e8 * 0.999f) {
      int ix = atomicAdd(counter, 1);
      flaglist[ix] = tok0 + t;
    }

    const float inv = 1.f / sum;
    const float rsc = 1.f / (esel + EPSV * sum);
    const size_t MN = (size_t)mtok * NG;
    const size_t base = (size_t)(tok0 + t) * NG + (li << 3);

    f32x4 r0, r1, m0, m1, s0, s1;
#pragma unroll
    for (int j = 0; j < 4; ++j) {
      float bitL = ((taken >> j) & 1u) ? 1.f : 0.f;
      float bitH = ((taken >> (j + 4)) & 1u) ? 1.f : 0.f;
      s0[j] = e[j] * inv;      s1[j] = e[j + 4] * inv;
      m0[j] = bitL;            m1[j] = bitH;
      r0[j] = bitL * e[j] * rsc;
      r1[j] = bitH * e[j + 4] * rsc;
    }
    *(f32x4*)&out[base]              = r0;
    *(f32x4*)&out[base + 4]          = r1;
    *(f32x4*)&out[MN + base]         = m0;
    *(f32x4*)&out[MN + base + 4]     = m1;
    *(f32x4*)&out[2 * MN + base]     = s0;
    *(f32x4*)&out[2 * MN + base + 4] = s1;
  }
}

// ---------------- Kernel 2: exact fp32 fixup, block-per-token ----------------
__global__ __launch_bounds__(256) void moe_fixup(
    const float* __restrict__ x, const float* __restrict__ W,
    float* __restrict__ out, const int* __restrict__ counter,
    const int* __restrict__ flaglist, int mtok)
{
  const int cnt = counter[0];
  const int g = threadIdx.x & 63;
  const int q = threadIdx.x >> 6;
  const size_t MN = (size_t)mtok * NG;
  __shared__ float part[4][64];

  for (int i = blockIdx.x; i < cnt; i += 256) {
    const int tok = flaglist[i];
    const float* xr = &x[(size_t)tok * DM + q * 512];
    const float* wr = &W[(size_t)g * DM + q * 512];
    f32x4 a = {0.f, 0.f, 0.f, 0.f};
#pragma unroll 8
    for (int k = 0; k < 512; k += 4)
      a += *(const f32x4*)&xr[k] * *(const f32x4*)&wr[k];
    part[q][g] = a.x + a.y + a.z + a.w;
    __syncthreads();

    if (q == 0) {
      float l = part[0][g] + part[1][g] + part[2][g] + part[3][g];

      float m = l;
#pragma unroll
      for (int msk = 1; msk < 64; msk <<= 1) m = fmaxf(m, __shfl_xor(m, msk));
      float e = __expf(l - m);
      float sum = e;
#pragma unroll
      for (int msk = 1; msk < 64; msk <<= 1) sum += __shfl_xor(sum, msk);

      bool sel = false;
#pragma unroll 1
      for (int p = 0; p < 8; ++p) {
        float bv = sel ? -3.4e38f : l;
        int bi = sel ? 1000 : g;
#pragma unroll
        for (int msk = 1; msk < 64; msk <<= 1) {
          float ov = __shfl_xor(bv, msk);
          int oi = __shfl_xor(bi, msk);
          bool better = (ov > bv) || (ov == bv && oi < bi);
          bv = better ? ov : bv;
          bi = better ? oi : bi;
        }
        if (bi == g) sel = true;
      }
      float esel = sel ? e : 0.f;
#pragma unroll
      for (int msk = 1; msk < 64; msk <<= 1) esel += __shfl_xor(esel, msk);

      const float inv = 1.f / sum;
      const float rsc = 1.f / (esel + EPSV * sum);
      const float bit = sel ? 1.f : 0.f;
      const size_t base = (size_t)tok * NG + g;
      out[base] = bit * e * rsc;
      out[MN + base] = bit;
      out[2 * MN + base] = e * inv;
    }
    __syncthreads();
  }
}

extern "C" void kernel_launch(void* const* d_in, const int* in_sizes, int n_in,
                              void* d_out, int out_size, void* d_ws, size_t ws_size,
                              hipStream_t stream) {
  const float* x = (const float*)d_in[0];
  const float* W = (const float*)d_in[1];
  float* out = (float*)d_out;
  const int mtok = in_sizes[0] / DM;          // 16384

  char* ws = (char*)d_ws;
  int* counter = (int*)ws;                               // @0
  int* flaglist = (int*)(ws + 4096);                     // 64 KB
  unsigned short* whp = (unsigned short*)(ws + 69632);   // 256 KB
  unsigned short* wlp = (unsigned short*)(ws + 331776);  // 256 KB

  hipLaunchKernelGGL(moe_prep, dim3(64), dim3(256), 0, stream, W, whp, wlp, counter);
  hipLaunchKernelGGL(moe_gemm, dim3(mtok / 16), dim3(256), 0, stream,
                     x, whp, wlp, out, counter, flaglist, mtok);
  hipLaunchKernelGGL(moe_fixup, dim3(256), dim3(256), 0, stream,
                     x, W, out, counter, flaglist, mtok);
}